// Round 1
// baseline (682.049 us; speedup 1.0000x reference)
//
#include <hip/hip_runtime.h>
#include <stdint.h>

#define B_ 4
#define S_ 2048
#define D_ 768
#define H_ 12
#define DK_ 64
#define F_ 3072

typedef __bf16 bf16x8 __attribute__((ext_vector_type(8)));
typedef unsigned short u16x8 __attribute__((ext_vector_type(8)));
typedef float f32x4 __attribute__((ext_vector_type(4)));

__device__ inline unsigned short f2bf(float f) {
    union { float f; unsigned u; } v; v.f = f;
    unsigned r = (v.u + 0x7FFFu + ((v.u >> 16) & 1u)) >> 16;
    return (unsigned short)r;
}
__device__ inline float b2f(unsigned short u) {
    union { unsigned u; float f; } v; v.u = ((unsigned)u) << 16;
    return v.f;
}
__device__ inline bf16x8 as_bf(u16x8 v) { return __builtin_bit_cast(bf16x8, v); }
__device__ inline f32x4 mfma16(u16x8 a, u16x8 b, f32x4 c) {
    return __builtin_amdgcn_mfma_f32_16x16x32_bf16(as_bf(a), as_bf(b), c, 0, 0, 0);
}
__device__ inline void gld16(const unsigned short* g, unsigned short* l) {
    __builtin_amdgcn_global_load_lds(
        (__attribute__((address_space(1))) void*)(unsigned short*)g,
        (__attribute__((address_space(3))) void*)l, 16, 0, 0);
}

// ---------------- fp32 -> bf16 convert ----------------
__global__ __launch_bounds__(256) void cvt_k(const float* __restrict__ in,
                                             unsigned short* __restrict__ out, int n) {
    int i = (blockIdx.x * 256 + threadIdx.x) * 4;
    if (i >= n) return;
    float4 v = *(const float4*)(in + i);
    out[i] = f2bf(v.x); out[i+1] = f2bf(v.y); out[i+2] = f2bf(v.z); out[i+3] = f2bf(v.w);
}

// ---------------- concat qkv bias ----------------
__global__ __launch_bounds__(256) void bias_k(const float* __restrict__ bq,
                                              const float* __restrict__ bk,
                                              const float* __restrict__ bv,
                                              float* __restrict__ out) {
    int i = blockIdx.x * 256 + threadIdx.x;
    if (i >= 2304) return;
    const float* s = (i < 768) ? bq : (i < 1536 ? bk : bv);
    out[i] = s[i % 768];
}

// ---------------- tiled transpose + convert: out[c][r] = bf16(in[r][c]) ----------------
__global__ __launch_bounds__(256) void tconv_k(const float* __restrict__ in,
                                               unsigned short* __restrict__ out,
                                               int inRS, int outRS, long inBS, long outBS) {
    __shared__ float tile[32][33];
    const float* ip = in + (long)blockIdx.z * inBS;
    unsigned short* op = out + (long)blockIdx.z * outBS;
    const int c0 = blockIdx.x * 32, r0 = blockIdx.y * 32;
    const int tx = threadIdx.x, ty = threadIdx.y;
    #pragma unroll
    for (int i = 0; i < 32; i += 8)
        tile[ty + i][tx] = ip[(long)(r0 + ty + i) * inRS + c0 + tx];
    __syncthreads();
    #pragma unroll
    for (int i = 0; i < 32; i += 8)
        op[(long)(c0 + ty + i) * outRS + r0 + tx] = f2bf(tile[tx][ty + i]);
}

// ---------------- MFMA GEMM: C[M,N] = A[M,K] * Bt[N,K]^T (+bias)(+res)(relu) ----------------
template<bool OUTBF, bool RELU, bool HASRES>
__global__ __launch_bounds__(256, 2) void gemm_k(const unsigned short* __restrict__ A,
                                                 const unsigned short* __restrict__ Bt,
                                                 const float* __restrict__ bias,
                                                 const float* __restrict__ res,
                                                 void* __restrict__ outp,
                                                 int M, int N, int K) {
    __shared__ unsigned short As[4096];   // [128][32]
    __shared__ unsigned short Bs[4096];   // [128][32]
    const int tid = threadIdx.x;
    const int w = tid >> 6, lane = tid & 63;
    const int m = lane & 15, quad = lane >> 4;
    const int wm = (w >> 1) * 64, wn = (w & 1) * 64;
    const long m0 = (long)blockIdx.x * 128, n0 = (long)blockIdx.y * 128;

    const int rowc = tid >> 2, colc = (tid & 3) * 8;   // 16B chunk per thread, x2 halves
    const unsigned short* aG0 = A + (m0 + rowc) * K + colc;
    const unsigned short* aG1 = A + (m0 + rowc + 64) * K + colc;
    const unsigned short* bG0 = Bt + (n0 + rowc) * K + colc;
    const unsigned short* bG1 = Bt + (n0 + rowc + 64) * K + colc;
    unsigned short* lA0 = As + w * 512;
    unsigned short* lA1 = As + 2048 + w * 512;
    unsigned short* lB0 = Bs + w * 512;
    unsigned short* lB1 = Bs + 2048 + w * 512;

    const f32x4 fz = {0.f, 0.f, 0.f, 0.f};
    f32x4 acc[4][4];
    #pragma unroll
    for (int i = 0; i < 4; i++)
        #pragma unroll
        for (int j = 0; j < 4; j++) acc[i][j] = fz;

    for (int k0 = 0; k0 < K; k0 += 32) {
        __syncthreads();
        gld16(aG0 + k0, lA0);
        gld16(aG1 + k0, lA1);
        gld16(bG0 + k0, lB0);
        gld16(bG1 + k0, lB1);
        __syncthreads();
        u16x8 af[4], bfr[4];
        #pragma unroll
        for (int i = 0; i < 4; i++) af[i] = *(const u16x8*)&As[(wm + i*16 + m)*32 + quad*8];
        #pragma unroll
        for (int j = 0; j < 4; j++) bfr[j] = *(const u16x8*)&Bs[(wn + j*16 + m)*32 + quad*8];
        #pragma unroll
        for (int i = 0; i < 4; i++)
            #pragma unroll
            for (int j = 0; j < 4; j++)
                acc[i][j] = mfma16(af[i], bfr[j], acc[i][j]);
    }

    #pragma unroll
    for (int j = 0; j < 4; j++) {
        const long col = n0 + wn + j*16 + m;
        const float bv = bias[col];
        #pragma unroll
        for (int i = 0; i < 4; i++) {
            #pragma unroll
            for (int r = 0; r < 4; r++) {
                const long row = m0 + wm + i*16 + quad*4 + r;
                float v = acc[i][j][r] + bv;
                if (HASRES) v += res[row * N + col];
                if (RELU)   v = fmaxf(v, 0.0f);
                if (OUTBF)  ((unsigned short*)outp)[row * N + col] = f2bf(v);
                else        ((float*)outp)[row * N + col] = v;
            }
        }
    }
}

// ---------------- flash attention ----------------
// qkv: [B*S, 3*D] bf16, layout cols: [h*64+d | Q], [768 + h*64+d | K], [1536 + h*64+d | V]
// out cat: [B*S, 768] bf16
__global__ __launch_bounds__(256, 2) void attn_k(const unsigned short* __restrict__ qkv,
                                                 unsigned short* __restrict__ cat) {
    __shared__ unsigned short Kl[2048];     // [32 kv][64 d]
    __shared__ unsigned short Vt[2048];     // [64 d][32 kv]
    __shared__ unsigned short Pl[4][512];   // per wave [16 q][32 kv]
    const int tid = threadIdx.x, w = tid >> 6, lane = tid & 63;
    const int m = lane & 15, quad = lane >> 4;
    const int b = blockIdx.y / H_, h = blockIdx.y % H_;
    const int q0 = blockIdx.x * 64 + w * 16;
    const long rb = (long)b * S_;
    const int LD = 3 * D_;   // 2304

    // Q fragments, pre-scaled by 1/sqrt(64)=0.125 (exact in bf16)
    u16x8 aq[2];
    {
        const unsigned short* qp = qkv + (rb + q0 + m) * (long)LD + h * DK_;
        #pragma unroll
        for (int kk = 0; kk < 2; kk++) {
            u16x8 raw = *(const u16x8*)(qp + kk*32 + quad*8);
            u16x8 sc;
            #pragma unroll
            for (int j = 0; j < 8; j++) sc[j] = f2bf(b2f(raw[j]) * 0.125f);
            aq[kk] = sc;
        }
    }

    const f32x4 fz = {0.f, 0.f, 0.f, 0.f};
    float mrow[4], lrow[4];
    f32x4 oacc[4];
    #pragma unroll
    for (int r = 0; r < 4; r++) { mrow[r] = -1e30f; lrow[r] = 0.f; }
    #pragma unroll
    for (int o = 0; o < 4; o++) oacc[o] = fz;

    const unsigned short* kb = qkv + rb * (long)LD + h * DK_ + D_;
    const unsigned short* vb = qkv + rb * (long)LD + h * DK_ + 2 * D_;
    const int vr = tid >> 3, vd = (tid & 7) * 8;

    for (int kv0 = 0; kv0 < S_; kv0 += 32) {
        __syncthreads();  // prior chunk fully consumed
        gld16(kb + (long)(kv0 + (tid >> 3)) * LD + (tid & 7) * 8, Kl + w * 512);
        u16x8 vv = *(const u16x8*)(vb + (long)(kv0 + vr) * LD + vd);
        #pragma unroll
        for (int jj = 0; jj < 8; jj++) Vt[(vd + jj) * 32 + vr] = vv[jj];
        __syncthreads();  // staging visible (compiler drains vmcnt/lgkmcnt)

        // S = Q*K^T  (16 x 32)
        f32x4 s[2];
        #pragma unroll
        for (int t = 0; t < 2; t++) {
            u16x8 b0 = *(const u16x8*)&Kl[(t*16 + m)*64 + quad*8];
            u16x8 b1 = *(const u16x8*)&Kl[(t*16 + m)*64 + 32 + quad*8];
            f32x4 z = fz;
            z = mfma16(aq[0], b0, z);
            z = mfma16(aq[1], b1, z);
            s[t] = z;
        }
        // online softmax (rows = quad*4+r, cols across 16 lanes)
        float al[4];
        #pragma unroll
        for (int r = 0; r < 4; r++) {
            float mx = fmaxf(s[0][r], s[1][r]);
            #pragma unroll
            for (int off = 1; off < 16; off <<= 1) mx = fmaxf(mx, __shfl_xor(mx, off, 64));
            float mn = fmaxf(mrow[r], mx);
            al[r] = __expf(mrow[r] - mn);
            mrow[r] = mn;
        }
        float p[2][4];
        #pragma unroll
        for (int t = 0; t < 2; t++)
            #pragma unroll
            for (int r = 0; r < 4; r++) p[t][r] = __expf(s[t][r] - mrow[r]);
        #pragma unroll
        for (int r = 0; r < 4; r++) {
            float su = p[0][r] + p[1][r];
            #pragma unroll
            for (int off = 1; off < 16; off <<= 1) su += __shfl_xor(su, off, 64);
            lrow[r] = lrow[r] * al[r] + su;
        }
        #pragma unroll
        for (int o = 0; o < 4; o++)
            #pragma unroll
            for (int r = 0; r < 4; r++) oacc[o][r] *= al[r];
        // P: C-layout -> LDS -> A-layout (per-wave region, same-wave lgkm wait only)
        #pragma unroll
        for (int t = 0; t < 2; t++)
            #pragma unroll
            for (int r = 0; r < 4; r++)
                Pl[w][(quad*4 + r)*32 + t*16 + m] = f2bf(p[t][r]);
        __asm__ volatile("s_waitcnt lgkmcnt(0)" ::: "memory");
        u16x8 ap = *(const u16x8*)&Pl[w][m*32 + quad*8];
        #pragma unroll
        for (int o = 0; o < 4; o++) {
            u16x8 bv2 = *(const u16x8*)&Vt[(o*16 + m)*32 + quad*8];
            oacc[o] = mfma16(ap, bv2, oacc[o]);
        }
    }

    #pragma unroll
    for (int o = 0; o < 4; o++)
        #pragma unroll
        for (int r = 0; r < 4; r++) {
            float v = oacc[o][r] / lrow[r];
            cat[(rb + q0 + quad*4 + r) * (long)D_ + h*DK_ + o*16 + m] = f2bf(v);
        }
}

// ---------------- layernorm: one row per block, 768 = 256*3 ----------------
__global__ __launch_bounds__(256) void ln_k(const float* __restrict__ in,
                                            const float* __restrict__ g,
                                            const float* __restrict__ be,
                                            float* __restrict__ outF,
                                            unsigned short* __restrict__ outB) {
    __shared__ float sm[4], sm2[4];
    const int t = threadIdx.x, w = t >> 6, lane = t & 63;
    const long row = blockIdx.x;
    const float* x = in + row * D_;
    float v0 = x[t], v1 = x[t + 256], v2 = x[t + 512];
    float s = v0 + v1 + v2;
    float s2 = v0*v0 + v1*v1 + v2*v2;
    #pragma unroll
    for (int off = 32; off >= 1; off >>= 1) {
        s  += __shfl_xor(s,  off, 64);
        s2 += __shfl_xor(s2, off, 64);
    }
    if (lane == 0) { sm[w] = s; sm2[w] = s2; }
    __syncthreads();
    s  = sm[0] + sm[1] + sm[2] + sm[3];
    s2 = sm2[0] + sm2[1] + sm2[2] + sm2[3];
    const float mu = s * (1.0f / D_);
    float var = s2 * (1.0f / D_) - mu * mu;
    var = fmaxf(var, 0.0f);
    const float rs = rsqrtf(var + 1e-5f);
    #pragma unroll
    for (int i = 0; i < 3; i++) {
        const int idx = t + i * 256;
        const float vv = (i == 0 ? v0 : (i == 1 ? v1 : v2));
        const float y = (vv - mu) * rs * g[idx] + be[idx];
        if (outF) outF[row * D_ + idx] = y;
        if (outB) outB[row * D_ + idx] = f2bf(y);
    }
}

extern "C" void kernel_launch(void* const* d_in, const int* in_sizes, int n_in,
                              void* d_out, int out_size, void* d_ws, size_t ws_size,
                              hipStream_t stream) {
    const float* src = (const float*)d_in[0];
    const float* Wq  = (const float*)d_in[1];
    const float* bq  = (const float*)d_in[2];
    const float* Wk  = (const float*)d_in[3];
    const float* bk  = (const float*)d_in[4];
    const float* Wv  = (const float*)d_in[5];
    const float* bv  = (const float*)d_in[6];
    const float* Wo  = (const float*)d_in[7];
    const float* bo  = (const float*)d_in[8];
    const float* g1  = (const float*)d_in[9];
    const float* be1 = (const float*)d_in[10];
    const float* W1  = (const float*)d_in[11];
    const float* bf1 = (const float*)d_in[12];
    const float* W2  = (const float*)d_in[13];
    const float* bf2 = (const float*)d_in[14];
    const float* g2  = (const float*)d_in[15];
    const float* be2 = (const float*)d_in[16];
    float* out = (float*)d_out;

    char* ws = (char*)d_ws;
    // liveness-checked overlap layout (~165 MB)
    unsigned short* XBF  = (unsigned short*)(ws);               // x bf16   [8192,768]
    unsigned short* CAT  = (unsigned short*)(ws + 12582912);    // attn out [8192,768]
    unsigned short* QKV  = (unsigned short*)(ws + 25165824);    // [8192,2304]
    float*          Y1   = (float*)(ws + 25165824);             // alias over QKV (qkv dead)
    unsigned short* WQT  = (unsigned short*)(ws + 62914560);    // [2304,768]
    unsigned short* WOT  = (unsigned short*)(ws + 66453504);    // [768,768]
    unsigned short* W1T  = (unsigned short*)(ws + 67633152);    // [3072,768]
    unsigned short* W2T  = (unsigned short*)(ws + 72351744);    // [768,3072]
    float*          BQKV = (float*)(ws + 77070336);             // [2304]
    float*          X1R  = (float*)(ws + 77079552);             // x1 fp32 [8192,768]
    unsigned short* X1B  = (unsigned short*)(ws + 102245376);   // x1 bf16
    unsigned short* Hb   = (unsigned short*)(ws + 114828288);   // ffn hidden [8192,3072]

    // conversions
    cvt_k<<<dim3(6144), 256, 0, stream>>>(src, XBF, 6291456);
    bias_k<<<dim3(9), 256, 0, stream>>>(bq, bk, bv, BQKV);
    dim3 tb(32, 8);
    // per-head QKV weights -> Bt rows n = sel*768 + h*64 + k, cols = d
    tconv_k<<<dim3(2, 24, 12), tb, 0, stream>>>(Wq, WQT,                64, 768, 49152L, 49152L);
    tconv_k<<<dim3(2, 24, 12), tb, 0, stream>>>(Wk, WQT + 589824,       64, 768, 49152L, 49152L);
    tconv_k<<<dim3(2, 24, 12), tb, 0, stream>>>(Wv, WQT + 1179648,      64, 768, 49152L, 49152L);
    tconv_k<<<dim3(24, 24, 1), tb, 0, stream>>>(Wo, WOT,                768, 768, 0L, 0L);
    tconv_k<<<dim3(96, 24, 1), tb, 0, stream>>>(W1, W1T,                3072, 768, 0L, 0L);
    tconv_k<<<dim3(24, 96, 1), tb, 0, stream>>>(W2, W2T,                768, 3072, 0L, 0L);

    // QKV projection: [8192,768] x [768,2304]
    gemm_k<true, false, false><<<dim3(64, 18), 256, 0, stream>>>(XBF, WQT, BQKV, nullptr, QKV, 8192, 2304, 768);
    // flash attention -> CAT
    attn_k<<<dim3(32, 48), 256, 0, stream>>>(QKV, CAT);
    // out projection + residual(source): Y1 = CAT @ Wo + bo + x
    gemm_k<false, false, true><<<dim3(64, 6), 256, 0, stream>>>(CAT, WOT, bo, src, Y1, 8192, 768, 768);
    // LN1 -> x1 (fp32 residual + bf16 activ)
    ln_k<<<dim3(8192), 256, 0, stream>>>(Y1, g1, be1, X1R, X1B);
    // FFN1 + ReLU
    gemm_k<true, true, false><<<dim3(64, 24), 256, 0, stream>>>(X1B, W1T, bf1, nullptr, Hb, 8192, 3072, 768);
    // FFN2 + residual(x1) -> d_out (fp32)
    gemm_k<false, false, true><<<dim3(64, 6), 256, 0, stream>>>(Hb, W2T, bf2, X1R, out, 8192, 768, 3072);
    // LN2 in-place on d_out
    ln_k<<<dim3(8192), 256, 0, stream>>>(out, g2, be2, out, nullptr);
}

// Round 2
// 491.051 us; speedup vs baseline: 1.3890x; 1.3890x over previous
//
#include <hip/hip_runtime.h>
#include <stdint.h>

#define B_ 4
#define S_ 2048
#define D_ 768
#define H_ 12
#define DK_ 64
#define F_ 3072

typedef __bf16 bf16x8 __attribute__((ext_vector_type(8)));
typedef unsigned short u16x8 __attribute__((ext_vector_type(8)));
typedef float f32x4 __attribute__((ext_vector_type(4)));

__device__ inline unsigned short f2bf(float f) {
    union { float f; unsigned u; } v; v.f = f;
    unsigned r = (v.u + 0x7FFFu + ((v.u >> 16) & 1u)) >> 16;
    return (unsigned short)r;
}
__device__ inline float b2f(unsigned short u) {
    union { unsigned u; float f; } v; v.u = ((unsigned)u) << 16;
    return v.f;
}
__device__ inline bf16x8 as_bf(u16x8 v) { return __builtin_bit_cast(bf16x8, v); }
__device__ inline f32x4 mfma16(u16x8 a, u16x8 b, f32x4 c) {
    return __builtin_amdgcn_mfma_f32_16x16x32_bf16(as_bf(a), as_bf(b), c, 0, 0, 0);
}
__device__ inline void gld16(const unsigned short* g, unsigned short* l) {
    __builtin_amdgcn_global_load_lds(
        (__attribute__((address_space(1))) void*)(unsigned short*)g,
        (__attribute__((address_space(3))) void*)l, 16, 0, 0);
}

// ---------------- fp32 -> bf16 convert ----------------
__global__ __launch_bounds__(256) void cvt_k(const float* __restrict__ in,
                                             unsigned short* __restrict__ out, int n) {
    int i = (blockIdx.x * 256 + threadIdx.x) * 4;
    if (i >= n) return;
    float4 v = *(const float4*)(in + i);
    out[i] = f2bf(v.x); out[i+1] = f2bf(v.y); out[i+2] = f2bf(v.z); out[i+3] = f2bf(v.w);
}

// ---------------- concat qkv bias ----------------
__global__ __launch_bounds__(256) void bias_k(const float* __restrict__ bq,
                                              const float* __restrict__ bk,
                                              const float* __restrict__ bv,
                                              float* __restrict__ out) {
    int i = blockIdx.x * 256 + threadIdx.x;
    if (i >= 2304) return;
    const float* s = (i < 768) ? bq : (i < 1536 ? bk : bv);
    out[i] = s[i % 768];
}

// ---------------- tiled transpose + convert: out[c][r] = bf16(in[r][c]) ----------------
__global__ __launch_bounds__(256) void tconv_k(const float* __restrict__ in,
                                               unsigned short* __restrict__ out,
                                               int inRS, int outRS, long inBS, long outBS) {
    __shared__ float tile[32][33];
    const float* ip = in + (long)blockIdx.z * inBS;
    unsigned short* op = out + (long)blockIdx.z * outBS;
    const int c0 = blockIdx.x * 32, r0 = blockIdx.y * 32;
    const int tx = threadIdx.x, ty = threadIdx.y;
    #pragma unroll
    for (int i = 0; i < 32; i += 8)
        tile[ty + i][tx] = ip[(long)(r0 + ty + i) * inRS + c0 + tx];
    __syncthreads();
    #pragma unroll
    for (int i = 0; i < 32; i += 8)
        op[(long)(c0 + ty + i) * outRS + r0 + tx] = f2bf(tile[tx][ty + i]);
}

// ---------------- MFMA GEMM: C[M,N] = A[M,K] * Bt[N,K]^T (+bias)(+res)(relu) ----------------
template<bool OUTBF, bool RELU, bool HASRES>
__global__ __launch_bounds__(256, 2) void gemm_k(const unsigned short* __restrict__ A,
                                                 const unsigned short* __restrict__ Bt,
                                                 const float* __restrict__ bias,
                                                 const float* __restrict__ res,
                                                 void* __restrict__ outp,
                                                 int M, int N, int K) {
    __shared__ unsigned short As[4096];   // [128][32]
    __shared__ unsigned short Bs[4096];   // [128][32]
    const int tid = threadIdx.x;
    const int w = tid >> 6, lane = tid & 63;
    const int m = lane & 15, quad = lane >> 4;
    const int wm = (w >> 1) * 64, wn = (w & 1) * 64;
    const long m0 = (long)blockIdx.x * 128, n0 = (long)blockIdx.y * 128;

    const int rowc = tid >> 2, colc = (tid & 3) * 8;   // 16B chunk per thread, x2 halves
    const unsigned short* aG0 = A + (m0 + rowc) * K + colc;
    const unsigned short* aG1 = A + (m0 + rowc + 64) * K + colc;
    const unsigned short* bG0 = Bt + (n0 + rowc) * K + colc;
    const unsigned short* bG1 = Bt + (n0 + rowc + 64) * K + colc;
    unsigned short* lA0 = As + w * 512;
    unsigned short* lA1 = As + 2048 + w * 512;
    unsigned short* lB0 = Bs + w * 512;
    unsigned short* lB1 = Bs + 2048 + w * 512;

    const f32x4 fz = {0.f, 0.f, 0.f, 0.f};
    f32x4 acc[4][4];
    #pragma unroll
    for (int i = 0; i < 4; i++)
        #pragma unroll
        for (int j = 0; j < 4; j++) acc[i][j] = fz;

    for (int k0 = 0; k0 < K; k0 += 32) {
        __syncthreads();
        gld16(aG0 + k0, lA0);
        gld16(aG1 + k0, lA1);
        gld16(bG0 + k0, lB0);
        gld16(bG1 + k0, lB1);
        __syncthreads();
        u16x8 af[4], bfr[4];
        #pragma unroll
        for (int i = 0; i < 4; i++) af[i] = *(const u16x8*)&As[(wm + i*16 + m)*32 + quad*8];
        #pragma unroll
        for (int j = 0; j < 4; j++) bfr[j] = *(const u16x8*)&Bs[(wn + j*16 + m)*32 + quad*8];
        #pragma unroll
        for (int i = 0; i < 4; i++)
            #pragma unroll
            for (int j = 0; j < 4; j++)
                acc[i][j] = mfma16(af[i], bfr[j], acc[i][j]);
    }

    #pragma unroll
    for (int j = 0; j < 4; j++) {
        const long col = n0 + wn + j*16 + m;
        const float bv = bias[col];
        #pragma unroll
        for (int i = 0; i < 4; i++) {
            #pragma unroll
            for (int r = 0; r < 4; r++) {
                const long row = m0 + wm + i*16 + quad*4 + r;
                float v = acc[i][j][r] + bv;
                if (HASRES) v += res[row * N + col];
                if (RELU)   v = fmaxf(v, 0.0f);
                if (OUTBF)  ((unsigned short*)outp)[row * N + col] = f2bf(v);
                else        ((float*)outp)[row * N + col] = v;
            }
        }
    }
}

// ---------------- flash attention v2 (S^T form, LDS-pipe minimized) ----------------
// qkv: [B*S, 3*D] bf16; out cat: [B*S, 768] bf16
// block = 4 waves; wave handles 32 q rows; KV chunk = 64, V double-buffered.
__global__ __launch_bounds__(256, 3) void attn_k(const unsigned short* __restrict__ qkv,
                                                 unsigned short* __restrict__ cat) {
    __shared__ unsigned short Vt[2][64 * 68];   // [buf][d][kv], stride 68 (bank-spread)
    __shared__ unsigned short Pl[4][32 * 72];   // per-wave [q 0..31][kv 0..63], stride 72

    const int tid = threadIdx.x, w = tid >> 6, lane = tid & 63;
    const int m = lane & 15, quad = lane >> 4;
    const int b = blockIdx.y / H_, h = blockIdx.y % H_;
    const int q0 = blockIdx.x * 128 + w * 32;
    const long rb = (long)b * S_;
    const int LD = 3 * D_;   // 2304

    const unsigned short* kb = qkv + rb * (long)LD + h * DK_ + D_;
    const unsigned short* vb = qkv + rb * (long)LD + h * DK_ + 2 * D_;

    // Q as MFMA B-fragments (B[n=q=lane&15][k=d=quad*8+j]), pre-scaled by 0.125 (exact)
    u16x8 qf[2][2];
    #pragma unroll
    for (int s = 0; s < 2; s++)
        #pragma unroll
        for (int ks = 0; ks < 2; ks++) {
            const unsigned short* qp = qkv + (rb + q0 + s*16 + m) * (long)LD + h*DK_ + ks*32 + quad*8;
            u16x8 raw = *(const u16x8*)qp;
            u16x8 sc;
            #pragma unroll
            for (int j = 0; j < 8; j++) sc[j] = f2bf(b2f(raw[j]) * 0.125f);
            qf[s][ks] = sc;
        }

    // V staging mapping: thread loads kv pair rows (vpr, vpr+1), 8 d-cols at vd
    const int vpr = (tid >> 3) * 2;
    const int vd  = (tid & 7) * 8;

    {   // preload chunk 0 V
        u16x8 v0 = *(const u16x8*)(vb + (long)(vpr)     * LD + vd);
        u16x8 v1 = *(const u16x8*)(vb + (long)(vpr + 1) * LD + vd);
        #pragma unroll
        for (int j = 0; j < 8; j++) {
            unsigned pk = (unsigned)v0[j] | ((unsigned)v1[j] << 16);
            *(unsigned*)&Vt[0][(vd + j)*68 + vpr] = pk;
        }
    }

    const f32x4 fz = {0.f, 0.f, 0.f, 0.f};
    float mrow[2] = {-1e30f, -1e30f};
    float lrow[2] = {0.f, 0.f};
    f32x4 oacc[2][4];
    #pragma unroll
    for (int s = 0; s < 2; s++)
        #pragma unroll
        for (int o = 0; o < 4; o++) oacc[s][o] = fz;

    for (int c = 0; c < S_/64; c++) {
        const int kv0 = c * 64;
        __syncthreads();   // Vt[c&1] visible; all waves done reading Vt[(c+1)&1]

        // issue next chunk's V global loads early (latency overlap with QK/softmax)
        u16x8 nv0, nv1;
        const bool havenext = (c + 1 < S_/64);
        if (havenext) {
            nv0 = *(const u16x8*)(vb + (long)(kv0 + 64 + vpr)     * LD + vd);
            nv1 = *(const u16x8*)(vb + (long)(kv0 + 64 + vpr + 1) * LD + vd);
        }

        // St = K * Q^T : St[s][t] rows kv = t*16+quad*4+r, col q = s*16+m (K frags direct from global)
        f32x4 st[2][4];
        #pragma unroll
        for (int s = 0; s < 2; s++)
            #pragma unroll
            for (int t = 0; t < 4; t++) st[s][t] = fz;
        #pragma unroll
        for (int t = 0; t < 4; t++) {
            #pragma unroll
            for (int ks = 0; ks < 2; ks++) {
                u16x8 kf = *(const u16x8*)(kb + (long)(kv0 + t*16 + m) * LD + ks*32 + quad*8);
                st[0][t] = mfma16(kf, qf[0][ks], st[0][t]);
                st[1][t] = mfma16(kf, qf[1][ks], st[1][t]);
            }
        }

        // online softmax per q-subtile; lane owns q = s*16+m, kv spread over (t, quad-reduced)
        #pragma unroll
        for (int s = 0; s < 2; s++) {
            float mx = st[s][0][0];
            #pragma unroll
            for (int t = 0; t < 4; t++)
                #pragma unroll
                for (int r = 0; r < 4; r++) mx = fmaxf(mx, st[s][t][r]);
            mx = fmaxf(mx, __shfl_xor(mx, 16));
            mx = fmaxf(mx, __shfl_xor(mx, 32));
            const float mn = fmaxf(mrow[s], mx);
            const float al = __expf(mrow[s] - mn);
            mrow[s] = mn;

            float su = 0.f;
            #pragma unroll
            for (int t = 0; t < 4; t++) {
                float p0 = __expf(st[s][t][0] - mn);
                float p1 = __expf(st[s][t][1] - mn);
                float p2 = __expf(st[s][t][2] - mn);
                float p3 = __expf(st[s][t][3] - mn);
                su += (p0 + p1) + (p2 + p3);
                uint2 pk;
                pk.x = (unsigned)f2bf(p0) | ((unsigned)f2bf(p1) << 16);
                pk.y = (unsigned)f2bf(p2) | ((unsigned)f2bf(p3) << 16);
                *(uint2*)&Pl[w][(s*16 + m)*72 + t*16 + quad*4] = pk;
            }
            su += __shfl_xor(su, 16);
            su += __shfl_xor(su, 32);
            lrow[s] = lrow[s] * al + su;

            // redistribute alpha to O-accumulator row layout (q = quad*4+r)
            float alr[4];
            #pragma unroll
            for (int r = 0; r < 4; r++) alr[r] = __shfl(al, quad*4 + r);
            #pragma unroll
            for (int o = 0; o < 4; o++)
                #pragma unroll
                for (int r = 0; r < 4; r++) oacc[s][o][r] *= alr[r];
        }

        __asm__ volatile("s_waitcnt lgkmcnt(0)" ::: "memory");  // own-wave Pl writes landed

        // P A-frags (A[m=q][k=kv]) from per-wave Pl
        u16x8 pf[2][2];
        #pragma unroll
        for (int s = 0; s < 2; s++)
            #pragma unroll
            for (int ks = 0; ks < 2; ks++)
                pf[s][ks] = *(const u16x8*)&Pl[w][(s*16 + m)*72 + ks*32 + quad*8];

        // O += P * V  (V^T B-frags: B[k=kv][n=d], row d = o*16+m of Vt)
        const unsigned short* vtb = Vt[c & 1];
        #pragma unroll
        for (int o = 0; o < 4; o++) {
            #pragma unroll
            for (int ks = 0; ks < 2; ks++) {
                union { u16x8 v; uint2 d[2]; } vf;
                vf.d[0] = *(const uint2*)&vtb[(o*16 + m)*68 + ks*32 + quad*8];
                vf.d[1] = *(const uint2*)&vtb[(o*16 + m)*68 + ks*32 + quad*8 + 4];
                oacc[0][o] = mfma16(pf[0][ks], vf.v, oacc[0][o]);
                oacc[1][o] = mfma16(pf[1][ks], vf.v, oacc[1][o]);
            }
        }

        // stage next V chunk into the other buffer (safe: consumers passed top barrier)
        if (havenext) {
            unsigned short* vtn = Vt[(c + 1) & 1];
            #pragma unroll
            for (int j = 0; j < 8; j++) {
                unsigned pk = (unsigned)nv0[j] | ((unsigned)nv1[j] << 16);
                *(unsigned*)&vtn[(vd + j)*68 + vpr] = pk;
            }
        }
    }

    // epilogue: divide by l (redistributed to O row layout) and store
    #pragma unroll
    for (int s = 0; s < 2; s++) {
        float lr[4];
        #pragma unroll
        for (int r = 0; r < 4; r++) lr[r] = __shfl(lrow[s], quad*4 + r);
        #pragma unroll
        for (int o = 0; o < 4; o++)
            #pragma unroll
            for (int r = 0; r < 4; r++) {
                float v = oacc[s][o][r] / lr[r];
                cat[(rb + q0 + s*16 + quad*4 + r) * (long)D_ + h*DK_ + o*16 + m] = f2bf(v);
            }
    }
}

// ---------------- layernorm: one row per block, 768 = 256*3 ----------------
__global__ __launch_bounds__(256) void ln_k(const float* __restrict__ in,
                                            const float* __restrict__ g,
                                            const float* __restrict__ be,
                                            float* __restrict__ outF,
                                            unsigned short* __restrict__ outB) {
    __shared__ float sm[4], sm2[4];
    const int t = threadIdx.x, w = t >> 6, lane = t & 63;
    const long row = blockIdx.x;
    const float* x = in + row * D_;
    float v0 = x[t], v1 = x[t + 256], v2 = x[t + 512];
    float s = v0 + v1 + v2;
    float s2 = v0*v0 + v1*v1 + v2*v2;
    #pragma unroll
    for (int off = 32; off >= 1; off >>= 1) {
        s  += __shfl_xor(s,  off, 64);
        s2 += __shfl_xor(s2, off, 64);
    }
    if (lane == 0) { sm[w] = s; sm2[w] = s2; }
    __syncthreads();
    s  = sm[0] + sm[1] + sm[2] + sm[3];
    s2 = sm2[0] + sm2[1] + sm2[2] + sm2[3];
    const float mu = s * (1.0f / D_);
    float var = s2 * (1.0f / D_) - mu * mu;
    var = fmaxf(var, 0.0f);
    const float rs = rsqrtf(var + 1e-5f);
    #pragma unroll
    for (int i = 0; i < 3; i++) {
        const int idx = t + i * 256;
        const float vv = (i == 0 ? v0 : (i == 1 ? v1 : v2));
        const float y = (vv - mu) * rs * g[idx] + be[idx];
        if (outF) outF[row * D_ + idx] = y;
        if (outB) outB[row * D_ + idx] = f2bf(y);
    }
}

extern "C" void kernel_launch(void* const* d_in, const int* in_sizes, int n_in,
                              void* d_out, int out_size, void* d_ws, size_t ws_size,
                              hipStream_t stream) {
    const float* src = (const float*)d_in[0];
    const float* Wq  = (const float*)d_in[1];
    const float* bq  = (const float*)d_in[2];
    const float* Wk  = (const float*)d_in[3];
    const float* bk  = (const float*)d_in[4];
    const float* Wv  = (const float*)d_in[5];
    const float* bv  = (const float*)d_in[6];
    const float* Wo  = (const float*)d_in[7];
    const float* bo  = (const float*)d_in[8];
    const float* g1  = (const float*)d_in[9];
    const float* be1 = (const float*)d_in[10];
    const float* W1  = (const float*)d_in[11];
    const float* bf1 = (const float*)d_in[12];
    const float* W2  = (const float*)d_in[13];
    const float* bf2 = (const float*)d_in[14];
    const float* g2  = (const float*)d_in[15];
    const float* be2 = (const float*)d_in[16];
    float* out = (float*)d_out;

    char* ws = (char*)d_ws;
    unsigned short* XBF  = (unsigned short*)(ws);               // x bf16   [8192,768]
    unsigned short* CAT  = (unsigned short*)(ws + 12582912);    // attn out [8192,768]
    unsigned short* QKV  = (unsigned short*)(ws + 25165824);    // [8192,2304]
    float*          Y1   = (float*)(ws + 25165824);             // alias over QKV (qkv dead)
    unsigned short* WQT  = (unsigned short*)(ws + 62914560);    // [2304,768]
    unsigned short* WOT  = (unsigned short*)(ws + 66453504);    // [768,768]
    unsigned short* W1T  = (unsigned short*)(ws + 67633152);    // [3072,768]
    unsigned short* W2T  = (unsigned short*)(ws + 72351744);    // [768,3072]
    float*          BQKV = (float*)(ws + 77070336);             // [2304]
    float*          X1R  = (float*)(ws + 77079552);             // x1 fp32 [8192,768]
    unsigned short* X1B  = (unsigned short*)(ws + 102245376);   // x1 bf16
    unsigned short* Hb   = (unsigned short*)(ws + 114828288);   // ffn hidden [8192,3072]

    cvt_k<<<dim3(6144), 256, 0, stream>>>(src, XBF, 6291456);
    bias_k<<<dim3(9), 256, 0, stream>>>(bq, bk, bv, BQKV);
    dim3 tb(32, 8);
    tconv_k<<<dim3(2, 24, 12), tb, 0, stream>>>(Wq, WQT,                64, 768, 49152L, 49152L);
    tconv_k<<<dim3(2, 24, 12), tb, 0, stream>>>(Wk, WQT + 589824,       64, 768, 49152L, 49152L);
    tconv_k<<<dim3(2, 24, 12), tb, 0, stream>>>(Wv, WQT + 1179648,      64, 768, 49152L, 49152L);
    tconv_k<<<dim3(24, 24, 1), tb, 0, stream>>>(Wo, WOT,                768, 768, 0L, 0L);
    tconv_k<<<dim3(96, 24, 1), tb, 0, stream>>>(W1, W1T,                3072, 768, 0L, 0L);
    tconv_k<<<dim3(24, 96, 1), tb, 0, stream>>>(W2, W2T,                768, 3072, 0L, 0L);

    gemm_k<true, false, false><<<dim3(64, 18), 256, 0, stream>>>(XBF, WQT, BQKV, nullptr, QKV, 8192, 2304, 768);
    attn_k<<<dim3(16, 48), 256, 0, stream>>>(QKV, CAT);
    gemm_k<false, false, true><<<dim3(64, 6), 256, 0, stream>>>(CAT, WOT, bo, src, Y1, 8192, 768, 768);
    ln_k<<<dim3(8192), 256, 0, stream>>>(Y1, g1, be1, X1R, X1B);
    gemm_k<true, true, false><<<dim3(64, 24), 256, 0, stream>>>(X1B, W1T, bf1, nullptr, Hb, 8192, 3072, 768);
    gemm_k<false, false, true><<<dim3(64, 6), 256, 0, stream>>>(Hb, W2T, bf2, X1R, out, 8192, 768, 3072);
    ln_k<<<dim3(8192), 256, 0, stream>>>(out, g2, be2, out, nullptr);
}